// Round 2
// baseline (91.828 us; speedup 1.0000x reference)
//
#include <hip/hip_runtime.h>
#include <hip/hip_bf16.h>

// ShapeletLearner: B=2048, Q=1024, K=32, L=64, S=993
// dist[b,s,l] = wsq[b,s] - (2/K)*cross[b,s,l] + ssq[l];  out = min_s(dist) @ fcw^T + fcb
// cross via bf16 MFMA; c2k=2^-4 folded into A (exact); -wsq in MFMA C operand.
// R8: occupancy/generation-smoothing probe.
//  - 512-thread blocks (8 waves), one block per batch (min stays block-local).
//  - wave w owns s in [128w, 128w+128): j-loop is 8 steps of 16 s each.
//  - phase-1 split by wave-half: waves 0-3 build the 8 bf16 shift-copies
//    (12 live floats), waves 4-7 compute wsq with load-time accumulation
//    (~20 live floats). Both halves run concurrently; no x[36] blob.
//  - __launch_bounds__(512,6): 3 blocks/CU = 6 waves/SIMD, VGPR cap 85 (est ~65).

#define B_   2048
#define Q_   1024
#define K_   32
#define L_   64
#define S_   993
#define CL   1048          // per-copy length (max read pos 1040+8)
#define WROW 12            // wsqT row: 8 j-values + 4 pad (48 B rows, 16B-aligned)

using frag_ab = __attribute__((ext_vector_type(8))) short;   // 8 bf16
using f32x4   = __attribute__((ext_vector_type(4))) float;

static __device__ __forceinline__ unsigned pack_bf16x2(float a, float b) {
    union { __hip_bfloat162 h; unsigned u; } cv;
    cv.h = __float22bfloat162_rn(make_float2(a, b));
    return cv.u;
}

// DPP row_shr max-scan step (16-lane rows). bound_ctrl=false + old=identity keeps
// the identity for shifted-in-from-outside lanes.
#define DPP_MAX_STEP(v, idf, ctrl)                                            \
    {                                                                         \
        union { float f; int i; } _in, _out;                                  \
        _in.f = v;                                                            \
        _out.i = __builtin_amdgcn_update_dpp(idf, _in.i, ctrl, 0xF, 0xF, false); \
        v = fmaxf(v, _out.f);                                                 \
    }

__global__ __launch_bounds__(512, 6)
void shapelet_mfma(const float* __restrict__ ts,
                   const float* __restrict__ shp,
                   const float* __restrict__ fcw,
                   const float* __restrict__ fcb,
                   float* __restrict__ out)
{
    __shared__ __align__(16) __hip_bfloat16 tsb[8][CL];            // 8 shift-copies
    __shared__ __align__(16) float          wsqT[8 * 16 * WROW];   // [w][n][j] = -wsq[128w+16j+n]
    __shared__ __align__(16) float          red[8][L_];

    const int tid  = threadIdx.x;
    const int b    = blockIdx.x;
    const int lane = tid & 63;
    const int w    = tid >> 6;       // wave 0..7
    const int n    = lane & 15;      // MFMA col (s within tile) / A row (l)
    const int q    = lane >> 4;      // MFMA quad

    const float* gts = ts + (size_t)b * Q_;

    // ---- epilogue params prefetched early ----
    float fw0 = 0.f, fw1 = 0.f, fb0 = 0.f, fb1 = 0.f;
    if (tid < L_) {
        fw0 = fcw[tid];
        fw1 = fcw[L_ + tid];
        fb0 = fcb[0];
        fb1 = fcb[1];
    }

    if (tid < 256) {
        // ---- waves 0-3: build 8 bf16 shift-copies straight from global ----
        // thread t holds ts[4t .. 4t+12) in regs, emits tsb[c][4t..4t+4) = ts[c+4t ..]
        const int j4 = 4 * tid;
        float x[12];
        #pragma unroll
        for (int u = 0; u < 3; ++u) {
            int e = j4 + 4 * u;
            e = e > (Q_ - 4) ? (Q_ - 4) : e;          // clamp (tail threads only)
            float4 t = *(const float4*)(gts + e);
            x[4*u+0] = t.x; x[4*u+1] = t.y; x[4*u+2] = t.z; x[4*u+3] = t.w;
        }
        if (tid >= 254) {                             // zero beyond series end
            #pragma unroll
            for (int u = 0; u < 12; ++u)
                if (j4 + u >= Q_) x[u] = 0.f;
        }
        #pragma unroll
        for (int c = 0; c < 8; ++c) {
            *(uint2*)&tsb[c][j4] = make_uint2(pack_bf16x2(x[c+0], x[c+1]),
                                              pack_bf16x2(x[c+2], x[c+3]));
        }
        // zero-pad [1024, 1048) for all copies
        if (tid < 48) {
            const int c  = tid / 6;
            const int x0 = Q_ + (tid - 6 * c) * 4;
            *(uint2*)&tsb[c][x0] = make_uint2(0u, 0u);
        }
    } else {
        // ---- waves 4-7: wsq, thread owns s = 4*t2 .. 4*t2+3, rolling ----
        const int t2 = tid - 256;
        float a4[4], b4[4];
        float s0 = 0.f, s1 = 0.f, s2 = 0.f, s3 = 0.f;
        #pragma unroll
        for (int u = 0; u < 9; ++u) {
            int e = 4 * t2 + 4 * u;
            e = e > (Q_ - 4) ? (Q_ - 4) : e;
            float4 t = *(const float4*)(gts + e);
            if (u == 0) { a4[0] = t.x; a4[1] = t.y; a4[2] = t.z; a4[3] = t.w; }
            if (u == 8) { b4[0] = t.x; b4[1] = t.y; b4[2] = t.z; b4[3] = t.w; }
            else {                                    // u = 0..7: x[0..31] -> sum
                s0 = fmaf(t.x, t.x, s0);
                s1 = fmaf(t.y, t.y, s1);
                s2 = fmaf(t.z, t.z, s2);
                s3 = fmaf(t.w, t.w, s3);
            }
        }
        float sq = (s0 + s1) + (s2 + s3);
        #pragma unroll
        for (int i = 0; i < 4; ++i) {
            const int s   = 4 * t2 + i;               // s in [0, 1024)
            const int r   = s & 127;
            const int row = (s >> 7) * 16 + (r & 15);
            wsqT[row * WROW + (r >> 4)] = (s < S_) ? sq * (-1.0f / K_) : -1e30f;
            sq += b4[i] * b4[i] - a4[i] * a4[i];
        }
    }

    // ---- A fragments (shapelets * 2^-4, exact) + in-register ssq partials ----
    frag_ab afrag[4];
    float   pf[4];
    #pragma unroll
    for (int f = 0; f < 4; ++f) {
        const float4* sp = (const float4*)(shp + (f * 16 + n) * K_ + q * 8);
        float4 x0 = sp[0], x1 = sp[1];
        pf[f] = x0.x*x0.x + x0.y*x0.y + x0.z*x0.z + x0.w*x0.w
              + x1.x*x1.x + x1.y*x1.y + x1.z*x1.z + x1.w*x1.w;
        union { frag_ab v; unsigned u[4]; } uu;
        uu.u[0] = pack_bf16x2(x0.x * 0.0625f, x0.y * 0.0625f);
        uu.u[1] = pack_bf16x2(x0.z * 0.0625f, x0.w * 0.0625f);
        uu.u[2] = pack_bf16x2(x1.x * 0.0625f, x1.y * 0.0625f);
        uu.u[3] = pack_bf16x2(x1.z * 0.0625f, x1.w * 0.0625f);
        afrag[f] = uu.v;
    }
    // reduce over the 4 q-lanes sharing row n
    #pragma unroll
    for (int f = 0; f < 4; ++f) {
        pf[f] += __shfl_xor(pf[f], 16, 64);
        pf[f] += __shfl_xor(pf[f], 32, 64);
    }
    __syncthreads();

    // ---- preload this lane's 8 (negated) wsq values: 2x ds_read_b128 ----
    float wq[8];
    {
        const float* wrow = &wsqT[(w * 16 + n) * WROW];
        f32x4 x0 = *(const f32x4*)(wrow);
        f32x4 x1 = *(const f32x4*)(wrow + 4);
        wq[0] = x0[0]; wq[1] = x0[1]; wq[2] = x0[2]; wq[3] = x0[3];
        wq[4] = x1[0]; wq[5] = x1[1]; wq[6] = x1[2]; wq[7] = x1[3];
    }

    // ---- main loop: wave w -> s in [128w, 128w+128); D = (2/K)*cross - wsq ----
    const __hip_bfloat16* bp = &tsb[n & 7][8 * q + (n & 8)];
    float rm[4][4];
    #pragma unroll
    for (int f = 0; f < 4; ++f)
        #pragma unroll
        for (int r = 0; r < 4; ++r) rm[f][r] = -3e38f;

    #pragma unroll
    for (int j = 0; j < 8; ++j) {
        frag_ab bv = *(const frag_ab*)(bp + w * 128 + 16 * j);
        const float nw = wq[j];
        f32x4 cin = {nw, nw, nw, nw};
        #pragma unroll
        for (int f = 0; f < 4; ++f) {
            f32x4 d = __builtin_amdgcn_mfma_f32_16x16x32_bf16(afrag[f], bv, cin, 0, 0, 0);
            #pragma unroll
            for (int r = 0; r < 4; ++r)
                rm[f][r] = fmaxf(rm[f][r], d[r]);
        }
    }

    // ---- max across the 16 s-cols (lanes n=0..15) on the VALU pipe via DPP scan ----
    {
        union { float f; int i; } idc; idc.f = -3e38f;
        const int idf = idc.i;
        #pragma unroll
        for (int f = 0; f < 4; ++f)
            #pragma unroll
            for (int r = 0; r < 4; ++r) {
                float v = rm[f][r];
                DPP_MAX_STEP(v, idf, 0x111);   // row_shr:1
                DPP_MAX_STEP(v, idf, 0x112);   // row_shr:2
                DPP_MAX_STEP(v, idf, 0x114);   // row_shr:4
                DPP_MAX_STEP(v, idf, 0x118);   // row_shr:8
                rm[f][r] = v;                  // lane n==15 holds the row max
            }
    }
    if (n == 15) {
        #pragma unroll
        for (int f = 0; f < 4; ++f) {
            f32x4 val = {rm[f][0], rm[f][1], rm[f][2], rm[f][3]};
            *(f32x4*)&red[w][f * 16 + q * 4] = val;
        }
    }
    __syncthreads();

    // ---- final: combine 8 waves, dist = ssq - ymax, FC, wave-64 reduce ----
    if (tid < L_) {
        const int l = tid;
        float y01 = fmaxf(red[0][l], red[1][l]);
        float y23 = fmaxf(red[2][l], red[3][l]);
        float y45 = fmaxf(red[4][l], red[5][l]);
        float y67 = fmaxf(red[6][l], red[7][l]);
        float y   = fmaxf(fmaxf(y01, y23), fmaxf(y45, y67));
        // lane l (n=l&15, q=l>>4) holds ssq_raw[f*16+n] in pf[f]; it needs f==q
        float sraw = (q & 2) ? ((q & 1) ? pf[3] : pf[2])
                             : ((q & 1) ? pf[1] : pf[0]);
        float d = sraw * (1.0f / K_) - y;
        float p0 = d * fw0;
        float p1 = d * fw1;
        #pragma unroll
        for (int off = 32; off > 0; off >>= 1) {
            p0 += __shfl_down(p0, off, 64);
            p1 += __shfl_down(p1, off, 64);
        }
        if (l == 0) {
            out[(size_t)b * 2 + 0] = p0 + fb0;
            out[(size_t)b * 2 + 1] = p1 + fb1;
        }
    }
}

extern "C" void kernel_launch(void* const* d_in, const int* in_sizes, int n_in,
                              void* d_out, int out_size, void* d_ws, size_t ws_size,
                              hipStream_t stream) {
    const float* ts  = (const float*)d_in[0];   // (B, Q) fp32
    const float* shp = (const float*)d_in[1];   // (L, K) fp32
    const float* fcw = (const float*)d_in[2];   // (2, L) fp32
    const float* fcb = (const float*)d_in[3];   // (2,)  fp32
    float* o = (float*)d_out;                   // (B, 2) fp32

    shapelet_mfma<<<B_, 512, 0, stream>>>(ts, shp, fcw, fcb, o);
}

// Round 3
// 78.222 us; speedup vs baseline: 1.1739x; 1.1739x over previous
//
#include <hip/hip_runtime.h>
#include <hip/hip_bf16.h>

// ShapeletLearner: B=2048, Q=1024, K=32, L=64, S=993
// dist[b,s,l] = wsq[b,s] - (2/K)*cross[b,s,l] + ssq[l];  out = min_s(dist) @ fcw^T + fcb
// cross via bf16 MFMA; c2k=2^-4 folded into A (exact); -wsq in MFMA C operand.
// R9: REVERT to the best harness-verified version (R0/78.77us).
// R7 (de-serialized pre-barrier phase) was neutral; R8 (512-thr deep-residency)
// regressed +7us (per-wave overhead x2, VGPR cap 85 -> spill risk). The dur_us
// metric is dominated by the harness poison fill (~41us @ ~80% HBM peak) plus
// the reset/restore dispatch train; kernel proper is single-digit us.

#define B_   2048
#define Q_   1024
#define K_   32
#define L_   64
#define S_   993
#define CL   1048          // per-copy length (max pos 1040+8)
#define WROW 20            // wsqT padded row (16 + 4): b128-aligned, conflict-light

using frag_ab = __attribute__((ext_vector_type(8))) short;   // 8 bf16
using f32x4   = __attribute__((ext_vector_type(4))) float;

static __device__ __forceinline__ unsigned pack_bf16x2(float a, float b) {
    union { __hip_bfloat162 h; unsigned u; } cv;
    cv.h = __float22bfloat162_rn(make_float2(a, b));
    return cv.u;
}

// DPP row_shr max-scan step (16-lane rows). bound_ctrl=false + old=identity keeps
// the identity for shifted-in-from-outside lanes.
#define DPP_MAX_STEP(v, idf, ctrl)                                            \
    {                                                                         \
        union { float f; int i; } _in, _out;                                  \
        _in.f = v;                                                            \
        _out.i = __builtin_amdgcn_update_dpp(idf, _in.i, ctrl, 0xF, 0xF, false); \
        v = fmaxf(v, _out.f);                                                 \
    }

__global__ __launch_bounds__(256, 4)
void shapelet_mfma(const float* __restrict__ ts,
                   const float* __restrict__ shp,
                   const float* __restrict__ fcw,
                   const float* __restrict__ fcb,
                   float* __restrict__ out)
{
    __shared__ __align__(16) __hip_bfloat16 tsb[8][CL];          // 8 shift-copies
    __shared__ __align__(16) float          wsqT[4 * 16 * WROW]; // [w][n][j] = -wsq[w*256+16j+n]
    __shared__ __align__(16) float          red[4][L_];
    __shared__ float                        ssq[L_];

    const int tid  = threadIdx.x;
    const int b    = blockIdx.x;
    const int lane = tid & 63;
    const int w    = tid >> 6;
    const int n    = lane & 15;      // MFMA col (s within tile) / A row (l)
    const int q    = lane >> 4;      // MFMA quad

    const float* gts = ts + (size_t)b * Q_;

    // ---- epilogue params prefetched early ----
    float fw0 = 0.f, fw1 = 0.f, fb0 = 0.f, fb1 = 0.f;
    if (tid < L_) {
        fw0 = fcw[tid];
        fw1 = fcw[L_ + tid];
        fb0 = fcb[0];
        fb1 = fcb[1];
    }

    // ---- build 8 bf16 shift-copies straight from global (no LDS reads) ----
    // thread j holds ts[4j .. 4j+12) in regs, emits tsb[c][4j..4j+4) = ts[c+4j ..] for c=0..7
    {
        const int j4 = 4 * tid;
        float v[12];
        #pragma unroll
        for (int u = 0; u < 3; ++u) {
            int e = j4 + 4 * u;
            e = e > (Q_ - 4) ? (Q_ - 4) : e;          // clamped (tail threads)
            float4 x = *(const float4*)(gts + e);
            v[4*u+0] = x.x; v[4*u+1] = x.y; v[4*u+2] = x.z; v[4*u+3] = x.w;
        }
        #pragma unroll
        for (int u = 0; u < 12; ++u)
            if (j4 + u >= Q_) v[u] = 0.f;             // zero beyond series end
        #pragma unroll
        for (int c = 0; c < 8; ++c) {
            *(uint2*)&tsb[c][j4] = make_uint2(pack_bf16x2(v[c+0], v[c+1]),
                                              pack_bf16x2(v[c+2], v[c+3]));
        }
        // zero-pad x in [1024, 1048) for all copies
        if (tid < 48) {
            const int c  = tid / 6;
            const int x0 = Q_ + (tid - 6 * c) * 4;
            *(uint2*)&tsb[c][x0] = make_uint2(0u, 0u);
        }
    }

    // ---- wsq: ONE wave, 16 s per thread, from global; store transposed & negated ----
    if (tid < 64) {
        const int d = tid;
        float vv[48];
        #pragma unroll
        for (int u = 0; u < 12; ++u) {
            int e = 16 * d + 4 * u;
            e = e > (Q_ - 4) ? (Q_ - 4) : e;
            float4 x = *(const float4*)(gts + e);
            vv[4*u+0] = x.x; vv[4*u+1] = x.y; vv[4*u+2] = x.z; vv[4*u+3] = x.w;
        }
        float sq = 0.f;
        #pragma unroll
        for (int k = 0; k < K_; ++k) sq = fmaf(vv[k], vv[k], sq);
        const int wv = d >> 4, jv = d & 15;
        #pragma unroll
        for (int i = 0; i < 16; ++i) {
            const int s = 16 * d + i;
            const float o = (s < S_) ? sq * (-1.0f / K_) : -1e30f;
            wsqT[(wv * 16 + i) * WROW + jv] = o;
            sq = sq + vv[32 + i] * vv[32 + i] - vv[i] * vv[i];
        }
    }

    // ---- ssq (exact fp32) ----
    if (tid < L_) {
        const float* sp = shp + tid * K_;
        float s = 0.f;
        #pragma unroll
        for (int k = 0; k < K_; ++k) s = fmaf(sp[k], sp[k], s);
        ssq[tid] = s * (1.0f / K_);
    }

    // ---- A fragments: shapelets * 2^-4 (exact scale), built once ----
    frag_ab afrag[4];
    #pragma unroll
    for (int f = 0; f < 4; ++f) {
        const float4* sp = (const float4*)(shp + (f * 16 + n) * K_ + q * 8);
        float4 x0 = sp[0], x1 = sp[1];
        union { frag_ab v; unsigned u[4]; } uu;
        uu.u[0] = pack_bf16x2(x0.x * 0.0625f, x0.y * 0.0625f);
        uu.u[1] = pack_bf16x2(x0.z * 0.0625f, x0.w * 0.0625f);
        uu.u[2] = pack_bf16x2(x1.x * 0.0625f, x1.y * 0.0625f);
        uu.u[3] = pack_bf16x2(x1.z * 0.0625f, x1.w * 0.0625f);
        afrag[f] = uu.v;
    }
    __syncthreads();

    // ---- preload this lane's 16 (negated) wsq values: 4x ds_read_b128 ----
    float wq[16];
    {
        const float* wrow = &wsqT[(w * 16 + n) * WROW];
        #pragma unroll
        for (int t = 0; t < 4; ++t) {
            f32x4 x = *(const f32x4*)(wrow + 4 * t);
            wq[4*t+0] = x[0]; wq[4*t+1] = x[1]; wq[4*t+2] = x[2]; wq[4*t+3] = x[3];
        }
    }

    // ---- main loop: wave w -> s-tiles [w*16, w*16+16); D = (2/K)*cross - wsq ----
    const __hip_bfloat16* bp = &tsb[n & 7][8 * q + (n & 8)];
    float rm[4][4];
    #pragma unroll
    for (int f = 0; f < 4; ++f)
        #pragma unroll
        for (int r = 0; r < 4; ++r) rm[f][r] = -3e38f;

    #pragma unroll
    for (int j = 0; j < 16; ++j) {
        frag_ab bv = *(const frag_ab*)(bp + w * 256 + 16 * j);
        const float nw = wq[j];
        f32x4 cin = {nw, nw, nw, nw};
        #pragma unroll
        for (int f = 0; f < 4; ++f) {
            f32x4 d = __builtin_amdgcn_mfma_f32_16x16x32_bf16(afrag[f], bv, cin, 0, 0, 0);
            #pragma unroll
            for (int r = 0; r < 4; ++r)
                rm[f][r] = fmaxf(rm[f][r], d[r]);
        }
    }

    // ---- max across the 16 s-cols (lanes n=0..15) on the VALU pipe via DPP scan ----
    {
        union { float f; int i; } idc; idc.f = -3e38f;
        const int idf = idc.i;
        #pragma unroll
        for (int f = 0; f < 4; ++f)
            #pragma unroll
            for (int r = 0; r < 4; ++r) {
                float v = rm[f][r];
                DPP_MAX_STEP(v, idf, 0x111);   // row_shr:1
                DPP_MAX_STEP(v, idf, 0x112);   // row_shr:2
                DPP_MAX_STEP(v, idf, 0x114);   // row_shr:4
                DPP_MAX_STEP(v, idf, 0x118);   // row_shr:8
                rm[f][r] = v;                  // lane n==15 holds the row max
            }
    }
    if (n == 15) {
        #pragma unroll
        for (int f = 0; f < 4; ++f) {
            f32x4 val = {rm[f][0], rm[f][1], rm[f][2], rm[f][3]};
            *(f32x4*)&red[w][f * 16 + q * 4] = val;
        }
    }
    __syncthreads();

    // ---- final: combine waves, dist = ssq - ymax, FC, wave-64 reduce ----
    if (tid < L_) {
        const int l = tid;
        float y = fmaxf(fmaxf(red[0][l], red[1][l]), fmaxf(red[2][l], red[3][l]));
        float d = ssq[l] - y;
        float p0 = d * fw0;
        float p1 = d * fw1;
        #pragma unroll
        for (int off = 32; off > 0; off >>= 1) {
            p0 += __shfl_down(p0, off, 64);
            p1 += __shfl_down(p1, off, 64);
        }
        if (l == 0) {
            out[(size_t)b * 2 + 0] = p0 + fb0;
            out[(size_t)b * 2 + 1] = p1 + fb1;
        }
    }
}

extern "C" void kernel_launch(void* const* d_in, const int* in_sizes, int n_in,
                              void* d_out, int out_size, void* d_ws, size_t ws_size,
                              hipStream_t stream) {
    const float* ts  = (const float*)d_in[0];   // (B, Q) fp32
    const float* shp = (const float*)d_in[1];   // (L, K) fp32
    const float* fcw = (const float*)d_in[2];   // (2, L) fp32
    const float* fcb = (const float*)d_in[3];   // (2,)  fp32
    float* o = (float*)d_out;                   // (B, 2) fp32

    shapelet_mfma<<<B_, 256, 0, stream>>>(ts, shp, fcw, fcb, o);
}